// Round 2
// baseline (6130.122 us; speedup 1.0000x reference)
//
#include <hip/hip_runtime.h>

typedef unsigned short ushort8 __attribute__((ext_vector_type(8)));

#define B_    4
#define S_    2048
#define HID_  2048
#define NH_   16
#define NKV_  8
#define D_    128
#define RK_   16
#define SCALING_ 0.08838834764831845f   // 128^-0.5
#define NEGBIG   -1.0e30f

__device__ __forceinline__ float bf2f(unsigned short u) {
  union { unsigned int i; float f; } x; x.i = ((unsigned int)u) << 16; return x.f;
}
__device__ __forceinline__ unsigned short f2bf(float f) {
  union { float f; unsigned int i; } x; x.f = f;
  unsigned int r = x.i + 0x7fffu + ((x.i >> 16) & 1u);
  return (unsigned short)(r >> 16);
}

// ---------------------------------------------------------------------------
// GEMM: C[M,N] = A[M,K] @ B[N,K]^T. A: f32 or bf16 (ABF). C: f32 or bf16 (CBF).
// 128x128 tile, BK=16, 256 threads, 8x8 micro-tile.
// ---------------------------------------------------------------------------
template<bool ABF, bool CBF>
__global__ __launch_bounds__(256) void gemm_nt(const void* __restrict__ A_,
                                               const float* __restrict__ Bm,
                                               void* __restrict__ C_,
                                               int M, int N, int K) {
  __shared__ float As[16][128];
  __shared__ float Bs[16][128];
  const int bm = blockIdx.y * 128;
  const int bn = blockIdx.x * 128;
  const int tid = threadIdx.x;
  const int tx = tid & 15, ty = tid >> 4;
  const int lr = tid >> 2;        // 0..63
  const int lk = (tid & 3) * 4;   // 0,4,8,12
  float acc[8][8] = {};
  for (int k0 = 0; k0 < K; k0 += 16) {
#pragma unroll
    for (int rr = 0; rr < 2; rr++) {
      const int row = lr + rr * 64;
      if (ABF) {
        const unsigned short* Ab = (const unsigned short*)A_;
        ushort4 u = *(const ushort4*)&Ab[(size_t)(bm + row) * K + k0 + lk];
        As[lk + 0][row] = bf2f(u.x); As[lk + 1][row] = bf2f(u.y);
        As[lk + 2][row] = bf2f(u.z); As[lk + 3][row] = bf2f(u.w);
      } else {
        const float* Af = (const float*)A_;
        float4 a4 = *(const float4*)&Af[(size_t)(bm + row) * K + k0 + lk];
        As[lk + 0][row] = a4.x; As[lk + 1][row] = a4.y;
        As[lk + 2][row] = a4.z; As[lk + 3][row] = a4.w;
      }
      float4 b4 = *(const float4*)&Bm[(size_t)(bn + row) * K + k0 + lk];
      Bs[lk + 0][row] = b4.x; Bs[lk + 1][row] = b4.y;
      Bs[lk + 2][row] = b4.z; Bs[lk + 3][row] = b4.w;
    }
    __syncthreads();
#pragma unroll
    for (int kk = 0; kk < 16; kk++) {
      float a[8], b[8];
      *(float4*)&a[0] = *(const float4*)&As[kk][ty * 8];
      *(float4*)&a[4] = *(const float4*)&As[kk][ty * 8 + 4];
      *(float4*)&b[0] = *(const float4*)&Bs[kk][tx * 8];
      *(float4*)&b[4] = *(const float4*)&Bs[kk][tx * 8 + 4];
#pragma unroll
      for (int i = 0; i < 8; i++)
#pragma unroll
        for (int j = 0; j < 8; j++)
          acc[i][j] += a[i] * b[j];
    }
    __syncthreads();
  }
#pragma unroll
  for (int i = 0; i < 8; i++) {
    const size_t ro = (size_t)(bm + ty * 8 + i) * N + bn + tx * 8;
    if (CBF) {
      unsigned short* C = (unsigned short*)C_;
      *(ushort4*)&C[ro] = make_ushort4(f2bf(acc[i][0]), f2bf(acc[i][1]),
                                       f2bf(acc[i][2]), f2bf(acc[i][3]));
      *(ushort4*)&C[ro + 4] = make_ushort4(f2bf(acc[i][4]), f2bf(acc[i][5]),
                                           f2bf(acc[i][6]), f2bf(acc[i][7]));
    } else {
      float* C = (float*)C_;
      *(float4*)&C[ro]     = make_float4(acc[i][0], acc[i][1], acc[i][2], acc[i][3]);
      *(float4*)&C[ro + 4] = make_float4(acc[i][4], acc[i][5], acc[i][6], acc[i][7]);
    }
  }
}

// ---------------------------------------------------------------------------
// In-place RoPE on bf16 q (B,S,NH,D). One thread per (b,s,h,d<64).
// ---------------------------------------------------------------------------
__global__ __launch_bounds__(256) void rope_q(unsigned short* __restrict__ q,
                                              const float* __restrict__ cosT,
                                              const float* __restrict__ sinT) {
  const int p = blockIdx.x * 256 + threadIdx.x;  // < 8,388,608
  const int d = p & 63;
  const int h = (p >> 6) & 15;
  const int s = (p >> 10) & 2047;
  const int b = p >> 21;
  const size_t base = (((size_t)b * S_ + s) * NH_ + h) * D_ + d;
  const float x1 = bf2f(q[base]), x2 = bf2f(q[base + 64]);
  const float c = cosT[s * 64 + d], sn = sinT[s * 64 + d];
  q[base]      = f2bf(x1 * c - x2 * sn);
  q[base + 64] = f2bf(x1 * sn + x2 * c);
}

// ---------------------------------------------------------------------------
// pk[b,s,h,r] = sum_d k_raw[b,s,h>>1,d] * Vr[h,d,r]
// pv[b,s,g,r] = sum_d v_raw[b,s,g,d]    * Zv[g,d,r]
// Block per (s,b), 256 threads.
// ---------------------------------------------------------------------------
__global__ __launch_bounds__(256) void pkpv_make(const unsigned short* __restrict__ k_raw,
                                                 const unsigned short* __restrict__ v_raw,
                                                 const float* __restrict__ Vr,
                                                 const float* __restrict__ Zv,
                                                 float* __restrict__ pk,
                                                 float* __restrict__ pv) {
  const int s = blockIdx.x, b = blockIdx.y;
  const int tid = threadIdx.x;
  __shared__ float kb[NKV_ * D_];
  __shared__ float vb[NKV_ * D_];
  {
    const size_t o = ((size_t)b * S_ + s) * (NKV_ * D_) + tid * 4;
    ushort4 ku = *(const ushort4*)&k_raw[o];
    kb[tid * 4 + 0] = bf2f(ku.x); kb[tid * 4 + 1] = bf2f(ku.y);
    kb[tid * 4 + 2] = bf2f(ku.z); kb[tid * 4 + 3] = bf2f(ku.w);
    ushort4 vu = *(const ushort4*)&v_raw[o];
    vb[tid * 4 + 0] = bf2f(vu.x); vb[tid * 4 + 1] = bf2f(vu.y);
    vb[tid * 4 + 2] = bf2f(vu.z); vb[tid * 4 + 3] = bf2f(vu.w);
  }
  __syncthreads();
  {
    const int h = tid >> 4, r = tid & 15, g = h >> 1;
    float a = 0.f;
    const float* vr = &Vr[(size_t)h * D_ * RK_ + r];
    const float* kk = &kb[g * D_];
#pragma unroll 8
    for (int d = 0; d < D_; d++) a += kk[d] * vr[d * RK_];
    pk[(((size_t)b * S_ + s) * NH_ + h) * RK_ + r] = a;
  }
  if (tid < 128) {
    const int g = tid >> 4, r = tid & 15;
    float a = 0.f;
    const float* zv = &Zv[(size_t)g * D_ * RK_ + r];
    const float* vv = &vb[g * D_];
#pragma unroll 8
    for (int d = 0; d < D_; d++) a += vv[d] * zv[d * RK_];
    pv[(((size_t)b * S_ + s) * NKV_ + g) * RK_ + r] = a;
  }
}

// ---------------------------------------------------------------------------
// BIG plan: expand pk -> k_rot bf16 (B,NH,S,D) with RoPE.
// Block = (s-tile, h, b), 256 threads, 32 rows/block.
// ---------------------------------------------------------------------------
__global__ __launch_bounds__(256) void expand_k(const float* __restrict__ pk,
                                                const float* __restrict__ Vr,
                                                const float* __restrict__ cosT,
                                                const float* __restrict__ sinT,
                                                unsigned short* __restrict__ kr) {
  const int s0 = blockIdx.x * 32, h = blockIdx.y, b = blockIdx.z;
  const int tid = threadIdx.x;
  __shared__ float pkS[32][17];
  if (tid < 128) {
    const int r_ = tid >> 2, c4 = (tid & 3) * 4;
    float4 v = *(const float4*)&pk[(((size_t)b * S_ + s0 + r_) * NH_ + h) * RK_ + c4];
    pkS[r_][c4 + 0] = v.x; pkS[r_][c4 + 1] = v.y;
    pkS[r_][c4 + 2] = v.z; pkS[r_][c4 + 3] = v.w;
  }
  __syncthreads();
  const int row = tid >> 3, dl = tid & 7;
  float kh[16];
#pragma unroll
  for (int j = 0; j < 16; j++) {
    const int d = dl + 8 * j;
    const float4* w = (const float4*)&Vr[((size_t)h * D_ + d) * RK_];
    float a = 0.f;
#pragma unroll
    for (int q4 = 0; q4 < 4; q4++) {
      float4 wv = w[q4];
      a += pkS[row][q4 * 4 + 0] * wv.x + pkS[row][q4 * 4 + 1] * wv.y
         + pkS[row][q4 * 4 + 2] * wv.z + pkS[row][q4 * 4 + 3] * wv.w;
    }
    kh[j] = a;
  }
  const int pos = s0 + row;
  const size_t o = (((size_t)b * NH_ + h) * S_ + pos) * D_;
#pragma unroll
  for (int j = 0; j < 8; j++) {
    const int d = dl + 8 * j;
    const float c = cosT[pos * 64 + d], sn = sinT[pos * 64 + d];
    kr[o + d]      = f2bf(kh[j] * c - kh[j + 8] * sn);
    kr[o + d + 64] = f2bf(kh[j] * sn + kh[j + 8] * c);
  }
}

// ---------------------------------------------------------------------------
// BIG plan: expand pv -> v_hat bf16 (B,NKV,S,D).
// ---------------------------------------------------------------------------
__global__ __launch_bounds__(256) void expand_v(const float* __restrict__ pv,
                                                const float* __restrict__ Zv,
                                                unsigned short* __restrict__ vh) {
  const int s0 = blockIdx.x * 32, g = blockIdx.y, b = blockIdx.z;
  const int tid = threadIdx.x;
  __shared__ float pvS[32][17];
  if (tid < 128) {
    const int r_ = tid >> 2, c4 = (tid & 3) * 4;
    float4 v = *(const float4*)&pv[(((size_t)b * S_ + s0 + r_) * NKV_ + g) * RK_ + c4];
    pvS[r_][c4 + 0] = v.x; pvS[r_][c4 + 1] = v.y;
    pvS[r_][c4 + 2] = v.z; pvS[r_][c4 + 3] = v.w;
  }
  __syncthreads();
  const int row = tid >> 3, dl = tid & 7;
  const size_t o = (((size_t)b * NKV_ + g) * S_ + s0 + row) * D_;
#pragma unroll
  for (int j = 0; j < 16; j++) {
    const int d = dl + 8 * j;
    const float4* w = (const float4*)&Zv[((size_t)g * D_ + d) * RK_];
    float a = 0.f;
#pragma unroll
    for (int q4 = 0; q4 < 4; q4++) {
      float4 wv = w[q4];
      a += pvS[row][q4 * 4 + 0] * wv.x + pvS[row][q4 * 4 + 1] * wv.y
         + pvS[row][q4 * 4 + 2] * wv.z + pvS[row][q4 * 4 + 3] * wv.w;
    }
    vh[o + d] = f2bf(a);
  }
}

// ---------------------------------------------------------------------------
// Flash attention. Block = (qt, h, b): 32 q-rows x 32-key tiles, 256 threads.
// REC=0: K/V from materialized kr/vh. REC=1: reconstruct from pk/pv in-kernel.
// ---------------------------------------------------------------------------
template<bool REC>
__global__ __launch_bounds__(256) void attn_fwd(const unsigned short* __restrict__ q,
                                                const unsigned short* __restrict__ kr,
                                                const unsigned short* __restrict__ vh,
                                                const float* __restrict__ pk,
                                                const float* __restrict__ pv,
                                                const float* __restrict__ Vr,
                                                const float* __restrict__ Zv,
                                                const float* __restrict__ cosT,
                                                const float* __restrict__ sinT,
                                                unsigned short* __restrict__ out) {
  const int qt = blockIdx.x, h = blockIdx.y, b = blockIdx.z;
  const int g = h >> 1;
  const int tid = threadIdx.x;

  __shared__ float Qs[D_][34];
  __shared__ float Ks[D_][34];
  __shared__ float Vs[32][132];
  __shared__ float Ps[32][33];
  __shared__ float mS[32], lS[32], aS[32];
  __shared__ float pkS[REC ? 32 : 1][17];
  __shared__ float pvS[REC ? 32 : 1][17];

  const int row = tid >> 3, dl = tid & 7, d0 = dl * 16;
  const int tq = tid >> 4, tk = tid & 15;

  // stage Q transposed (once)
  {
    const unsigned short* qp = &q[(((size_t)b * S_ + qt * 32 + row) * NH_ + h) * D_ + d0];
    ushort8 u0 = *(const ushort8*)qp, u1 = *(const ushort8*)(qp + 8);
#pragma unroll
    for (int j = 0; j < 8; j++) {
      Qs[d0 + j][row]     = bf2f(u0[j]);
      Qs[d0 + 8 + j][row] = bf2f(u1[j]);
    }
  }
  if (tid < 32) { mS[tid] = NEGBIG; lS[tid] = 0.f; }

  float O[16] = {};

  for (int kt = 0; kt <= qt; kt++) {
    __syncthreads();  // prev iteration's consumers done
    if constexpr (!REC) {
      const unsigned short* kp = &kr[(((size_t)b * NH_ + h) * S_ + kt * 32 + row) * D_ + d0];
      ushort8 k0v = *(const ushort8*)kp, k1v = *(const ushort8*)(kp + 8);
      const unsigned short* vp = &vh[(((size_t)b * NKV_ + g) * S_ + kt * 32 + row) * D_ + d0];
      ushort8 v0v = *(const ushort8*)vp, v1v = *(const ushort8*)(vp + 8);
#pragma unroll
      for (int j = 0; j < 8; j++) {
        Ks[d0 + j][row]     = bf2f(k0v[j]);
        Ks[d0 + 8 + j][row] = bf2f(k1v[j]);
        Vs[row][d0 + j]     = bf2f(v0v[j]);
        Vs[row][d0 + 8 + j] = bf2f(v1v[j]);
      }
      __syncthreads();
    } else {
      if (tid < 128) {
        const int r_ = tid >> 2, c4 = (tid & 3) * 4;
        float4 a = *(const float4*)&pk[(((size_t)b * S_ + kt * 32 + r_) * NH_ + h) * RK_ + c4];
        pkS[r_][c4 + 0] = a.x; pkS[r_][c4 + 1] = a.y;
        pkS[r_][c4 + 2] = a.z; pkS[r_][c4 + 3] = a.w;
        float4 c = *(const float4*)&pv[(((size_t)b * S_ + kt * 32 + r_) * NKV_ + g) * RK_ + c4];
        pvS[r_][c4 + 0] = c.x; pvS[r_][c4 + 1] = c.y;
        pvS[r_][c4 + 2] = c.z; pvS[r_][c4 + 3] = c.w;
      }
      __syncthreads();
      float kh[16];
#pragma unroll
      for (int j = 0; j < 16; j++) {
        const int d = dl + 8 * j;
        const float4* w = (const float4*)&Vr[((size_t)h * D_ + d) * RK_];
        float a = 0.f;
#pragma unroll
        for (int q4 = 0; q4 < 4; q4++) {
          float4 wv = w[q4];
          a += pkS[row][q4 * 4 + 0] * wv.x + pkS[row][q4 * 4 + 1] * wv.y
             + pkS[row][q4 * 4 + 2] * wv.z + pkS[row][q4 * 4 + 3] * wv.w;
        }
        kh[j] = a;
      }
      {
        const int pos = kt * 32 + row;
#pragma unroll
        for (int j = 0; j < 8; j++) {
          const int d = dl + 8 * j;
          const float c = cosT[pos * 64 + d], sn = sinT[pos * 64 + d];
          Ks[d][row]      = kh[j] * c - kh[j + 8] * sn;
          Ks[d + 64][row] = kh[j] * sn + kh[j + 8] * c;
        }
      }
#pragma unroll
      for (int j = 0; j < 16; j++) {
        const int d = dl + 8 * j;
        const float4* w = (const float4*)&Zv[((size_t)g * D_ + d) * RK_];
        float a = 0.f;
#pragma unroll
        for (int q4 = 0; q4 < 4; q4++) {
          float4 wv = w[q4];
          a += pvS[row][q4 * 4 + 0] * wv.x + pvS[row][q4 * 4 + 1] * wv.y
             + pvS[row][q4 * 4 + 2] * wv.z + pvS[row][q4 * 4 + 3] * wv.w;
        }
        Vs[row][d] = a;
      }
      __syncthreads();
    }

    // scores: 2x2 per thread
    float s00 = 0.f, s01 = 0.f, s10 = 0.f, s11 = 0.f;
#pragma unroll 8
    for (int d = 0; d < D_; d++) {
      const float2 qv = *(const float2*)&Qs[d][tq * 2];
      const float2 kv = *(const float2*)&Ks[d][tk * 2];
      s00 += qv.x * kv.x; s01 += qv.x * kv.y;
      s10 += qv.y * kv.x; s11 += qv.y * kv.y;
    }
    const int qg0 = qt * 32 + tq * 2, kg0 = kt * 32 + tk * 2;
    Ps[tq * 2 + 0][tk * 2 + 0] = (kg0     <= qg0    ) ? s00 * SCALING_ : NEGBIG;
    Ps[tq * 2 + 0][tk * 2 + 1] = (kg0 + 1 <= qg0    ) ? s01 * SCALING_ : NEGBIG;
    Ps[tq * 2 + 1][tk * 2 + 0] = (kg0     <= qg0 + 1) ? s10 * SCALING_ : NEGBIG;
    Ps[tq * 2 + 1][tk * 2 + 1] = (kg0 + 1 <= qg0 + 1) ? s11 * SCALING_ : NEGBIG;
    __syncthreads();

    // online softmax (threads 0..31, one per q-row)
    if (tid < 32) {
      const float m_old = mS[tid];
      float mx = m_old;
#pragma unroll
      for (int k = 0; k < 32; k++) mx = fmaxf(mx, Ps[tid][k]);
      const float al = __expf(m_old - mx);
      float sum = 0.f;
#pragma unroll
      for (int k = 0; k < 32; k++) {
        const float e = __expf(Ps[tid][k] - mx);
        Ps[tid][k] = e;
        sum += e;
      }
      lS[tid] = lS[tid] * al + sum;
      mS[tid] = mx;
      aS[tid] = al;
    }
    __syncthreads();

    // rescale + PV accumulate (float4 V reads; thread owns cols dl*4 + 32*jj + c)
    const float al = aS[row];
#pragma unroll
    for (int jj = 0; jj < 16; jj++) O[jj] *= al;
#pragma unroll 4
    for (int k = 0; k < 32; k++) {
      const float p = Ps[row][k];
#pragma unroll
      for (int jj = 0; jj < 4; jj++) {
        const float4 v = *(const float4*)&Vs[k][dl * 4 + 32 * jj];
        O[jj * 4 + 0] += p * v.x; O[jj * 4 + 1] += p * v.y;
        O[jj * 4 + 2] += p * v.z; O[jj * 4 + 3] += p * v.w;
      }
    }
  }

  const float inv = 1.f / lS[row];
  const size_t ob = ((size_t)b * S_ + qt * 32 + row) * (NH_ * D_) + h * D_;
#pragma unroll
  for (int jj = 0; jj < 4; jj++) {
    *(ushort4*)&out[ob + dl * 4 + 32 * jj] =
        make_ushort4(f2bf(O[jj * 4 + 0] * inv), f2bf(O[jj * 4 + 1] * inv),
                     f2bf(O[jj * 4 + 2] * inv), f2bf(O[jj * 4 + 3] * inv));
  }
}

// ---------------------------------------------------------------------------
// Host launch
// ---------------------------------------------------------------------------
extern "C" void kernel_launch(void* const* d_in, const int* in_sizes, int n_in,
                              void* d_out, int out_size, void* d_ws, size_t ws_size,
                              hipStream_t stream) {
  const float* hidden = (const float*)d_in[0];
  const float* cosT   = (const float*)d_in[1];
  const float* sinT   = (const float*)d_in[2];
  const float* W_q    = (const float*)d_in[5];
  const float* W_k    = (const float*)d_in[6];
  const float* W_v    = (const float*)d_in[7];
  const float* W_o    = (const float*)d_in[8];
  const float* Vr     = (const float*)d_in[9];
  const float* Zv     = (const float*)d_in[10];
  float* out = (float*)d_out;

  // workspace layout (bytes)
  char* ws = (char*)d_ws;
  unsigned short* q_b    = (unsigned short*)(ws + 0);           // 33,554,432 B bf16 (B,S,NH,D)
  unsigned short* kraw_b = (unsigned short*)(ws + 33554432);    // 16,777,216 B bf16 (B,S,NKV,D)
  unsigned short* vraw_b = (unsigned short*)(ws + 50331648);    // 16,777,216 B
  unsigned short* attn_b = (unsigned short*)(ws + 33554432);    // alias over kraw+vraw (dead by then)
  float*          pk_f   = (float*)(ws + 67108864);             //  8,388,608 B (B,S,NH,RK)
  float*          pv_f   = (float*)(ws + 75497472);             //  4,194,304 B (B,S,NKV,RV)
  unsigned short* kr_b   = (unsigned short*)(ws + 79691776);    // 33,554,432 B (B,NH,S,D)  [BIG]
  unsigned short* vh_b   = (unsigned short*)(ws + 113246208);   // 16,777,216 B (B,NKV,S,D) [BIG]
  const size_t NEED_BIG = 130023424;
  const bool big = (ws_size >= NEED_BIG);

  const int M = B_ * S_;  // 8192

  // 1) projections (f32 in, bf16 out)
  gemm_nt<false, true><<<dim3(16, 64), 256, 0, stream>>>(hidden, W_q, q_b,    M, NH_ * D_,  HID_);
  gemm_nt<false, true><<<dim3( 8, 64), 256, 0, stream>>>(hidden, W_k, kraw_b, M, NKV_ * D_, HID_);
  gemm_nt<false, true><<<dim3( 8, 64), 256, 0, stream>>>(hidden, W_v, vraw_b, M, NKV_ * D_, HID_);

  // 2) rope(q) in place
  rope_q<<<(B_ * S_ * NH_ * 64) / 256, 256, 0, stream>>>(q_b, cosT, sinT);

  // 3) low-rank coefficients
  pkpv_make<<<dim3(S_, B_), 256, 0, stream>>>(kraw_b, vraw_b, Vr, Zv, pk_f, pv_f);

  // 4) attention
  if (big) {
    expand_k<<<dim3(S_ / 32, NH_, B_), 256, 0, stream>>>(pk_f, Vr, cosT, sinT, kr_b);
    expand_v<<<dim3(S_ / 32, NKV_, B_), 256, 0, stream>>>(pv_f, Zv, vh_b);
    attn_fwd<false><<<dim3(S_ / 32, NH_, B_), 256, 0, stream>>>(
        q_b, kr_b, vh_b, pk_f, pv_f, Vr, Zv, cosT, sinT, attn_b);
  } else {
    attn_fwd<true><<<dim3(S_ / 32, NH_, B_), 256, 0, stream>>>(
        q_b, nullptr, nullptr, pk_f, pv_f, Vr, Zv, cosT, sinT, attn_b);
  }

  // 5) output projection (bf16 A, f32 out)
  gemm_nt<true, false><<<dim3(16, 64), 256, 0, stream>>>(attn_b, W_o, out, M, HID_, HID_);
}

// Round 3
// 951.663 us; speedup vs baseline: 6.4415x; 6.4415x over previous
//
#include <hip/hip_runtime.h>

typedef unsigned short ushort8 __attribute__((ext_vector_type(8)));
typedef short s16x8 __attribute__((ext_vector_type(8)));
typedef float f32x4 __attribute__((ext_vector_type(4)));

#define AS1 __attribute__((address_space(1)))
#define AS3 __attribute__((address_space(3)))

#define B_    4
#define S_    2048
#define HID_  2048
#define NH_   16
#define NKV_  8
#define D_    128
#define RK_   16
#define SCALING_ 0.08838834764831845f   // 128^-0.5
#define NEGBIG   -1.0e30f

__device__ __forceinline__ float bf2f(unsigned short u) {
  union { unsigned int i; float f; } x; x.i = ((unsigned int)u) << 16; return x.f;
}
__device__ __forceinline__ unsigned short f2bf(float f) {
  union { float f; unsigned int i; } x; x.f = f;
  unsigned int r = x.i + 0x7fffu + ((x.i >> 16) & 1u);
  return (unsigned short)(r >> 16);
}

// ---------------------------------------------------------------------------
// f32 -> bf16 conversion, 8 elems/thread, grid-stride.
// ---------------------------------------------------------------------------
__global__ __launch_bounds__(256) void cvt_bf16(const float* __restrict__ in,
                                                unsigned short* __restrict__ out,
                                                int n8) {
  int i = blockIdx.x * 256 + threadIdx.x;
  const int stride = gridDim.x * 256;
  for (; i < n8; i += stride) {
    const float4 a = ((const float4*)in)[i * 2];
    const float4 b = ((const float4*)in)[i * 2 + 1];
    ushort8 u;
    u[0] = f2bf(a.x); u[1] = f2bf(a.y); u[2] = f2bf(a.z); u[3] = f2bf(a.w);
    u[4] = f2bf(b.x); u[5] = f2bf(b.y); u[6] = f2bf(b.z); u[7] = f2bf(b.w);
    *(ushort8*)&out[i * 8] = u;
  }
}

// ---------------------------------------------------------------------------
// MFMA GEMM: C[M,N] = A[M,K] @ B[N,K]^T, A,B bf16, C f32 or bf16.
// 128x128 tile, BK=64, 256 threads = 4 waves (2x2), per-wave 64x64 (4x4 frags).
// Both operands staged via global_load_lds (linear dest) with pre-swizzled
// source (slot ^= row&7) -> conflict-free ds_read_b128.
// ---------------------------------------------------------------------------
template<bool CBF>
__global__ __launch_bounds__(256) void gemm_mfma(const unsigned short* __restrict__ A,
                                                 const unsigned short* __restrict__ Bb,
                                                 void* __restrict__ C_,
                                                 int M, int N, int K) {
  __shared__ unsigned short Ash[128 * 64];
  __shared__ unsigned short Bsh[128 * 64];
  const int tid = threadIdx.x;
  const int w = tid >> 6, l = tid & 63, lg = l >> 4, ll = l & 15;
  const int wr = w >> 1, wc = w & 1;
  const int bm = blockIdx.y * 128, bn = blockIdx.x * 128;

  f32x4 acc[4][4];
#pragma unroll
  for (int i = 0; i < 4; i++)
#pragma unroll
    for (int j = 0; j < 4; j++) acc[i][j] = (f32x4){0.f, 0.f, 0.f, 0.f};

  const int srow = tid >> 3;        // 0..31 within a 32-row staging chunk
  const int sslot = tid & 7;        // 16B slot 0..7

  for (int k0 = 0; k0 < K; k0 += 64) {
    __syncthreads();
#pragma unroll
    for (int c = 0; c < 4; ++c) {
      const int row = c * 32 + srow;
      const int ss = sslot ^ (row & 7);
      const unsigned short* srcA = &A[(size_t)(bm + row) * K + k0 + ss * 8];
      const unsigned short* srcB = &Bb[(size_t)(bn + row) * K + k0 + ss * 8];
      char* dstA = ((char*)Ash) + c * 4096 + w * 1024;
      char* dstB = ((char*)Bsh) + c * 4096 + w * 1024;
      __builtin_amdgcn_global_load_lds((const AS1 void*)srcA, (AS3 void*)dstA, 16, 0, 0);
      __builtin_amdgcn_global_load_lds((const AS1 void*)srcB, (AS3 void*)dstB, 16, 0, 0);
    }
    __syncthreads();

#pragma unroll
    for (int ks = 0; ks < 2; ++ks) {
      s16x8 af[4], bf_[4];
#pragma unroll
      for (int mi = 0; mi < 4; ++mi) {
        const int row = wr * 64 + mi * 16 + ll;
        af[mi] = *(const s16x8*)&Ash[row * 64 + (((ks * 4 + lg) ^ (row & 7)) * 8)];
      }
#pragma unroll
      for (int ni = 0; ni < 4; ++ni) {
        const int row = wc * 64 + ni * 16 + ll;
        bf_[ni] = *(const s16x8*)&Bsh[row * 64 + (((ks * 4 + lg) ^ (row & 7)) * 8)];
      }
#pragma unroll
      for (int mi = 0; mi < 4; ++mi)
#pragma unroll
        for (int ni = 0; ni < 4; ++ni)
          acc[mi][ni] = __builtin_amdgcn_mfma_f32_16x16x32_bf16(af[mi], bf_[ni], acc[mi][ni], 0, 0, 0);
    }
  }

#pragma unroll
  for (int mi = 0; mi < 4; ++mi)
#pragma unroll
    for (int ni = 0; ni < 4; ++ni)
#pragma unroll
      for (int j = 0; j < 4; ++j) {
        const int row = bm + wr * 64 + mi * 16 + lg * 4 + j;
        const int col = bn + wc * 64 + ni * 16 + ll;
        if (CBF) ((unsigned short*)C_)[(size_t)row * N + col] = f2bf(acc[mi][ni][j]);
        else     ((float*)C_)[(size_t)row * N + col] = acc[mi][ni][j];
      }
}

// ---------------------------------------------------------------------------
// In-place RoPE on bf16 q (B,S,NH,D).
// ---------------------------------------------------------------------------
__global__ __launch_bounds__(256) void rope_q(unsigned short* __restrict__ q,
                                              const float* __restrict__ cosT,
                                              const float* __restrict__ sinT) {
  const int p = blockIdx.x * 256 + threadIdx.x;
  const int d = p & 63;
  const int h = (p >> 6) & 15;
  const int s = (p >> 10) & 2047;
  const int b = p >> 21;
  const size_t base = (((size_t)b * S_ + s) * NH_ + h) * D_ + d;
  const float x1 = bf2f(q[base]), x2 = bf2f(q[base + 64]);
  const float c = cosT[s * 64 + d], sn = sinT[s * 64 + d];
  q[base]      = f2bf(x1 * c - x2 * sn);
  q[base + 64] = f2bf(x1 * sn + x2 * c);
}

// ---------------------------------------------------------------------------
// pk / pv low-rank coefficients. Block per (s,b), 256 threads.
// ---------------------------------------------------------------------------
__global__ __launch_bounds__(256) void pkpv_make(const unsigned short* __restrict__ k_raw,
                                                 const unsigned short* __restrict__ v_raw,
                                                 const float* __restrict__ Vr,
                                                 const float* __restrict__ Zv,
                                                 float* __restrict__ pk,
                                                 float* __restrict__ pv) {
  const int s = blockIdx.x, b = blockIdx.y;
  const int tid = threadIdx.x;
  __shared__ float kb[NKV_ * D_];
  __shared__ float vb[NKV_ * D_];
  {
    const size_t o = ((size_t)b * S_ + s) * (NKV_ * D_) + tid * 4;
    ushort4 ku = *(const ushort4*)&k_raw[o];
    kb[tid * 4 + 0] = bf2f(ku.x); kb[tid * 4 + 1] = bf2f(ku.y);
    kb[tid * 4 + 2] = bf2f(ku.z); kb[tid * 4 + 3] = bf2f(ku.w);
    ushort4 vu = *(const ushort4*)&v_raw[o];
    vb[tid * 4 + 0] = bf2f(vu.x); vb[tid * 4 + 1] = bf2f(vu.y);
    vb[tid * 4 + 2] = bf2f(vu.z); vb[tid * 4 + 3] = bf2f(vu.w);
  }
  __syncthreads();
  {
    const int h = tid >> 4, r = tid & 15, g = h >> 1;
    float a = 0.f;
    const float* vr = &Vr[(size_t)h * D_ * RK_ + r];
    const float* kk = &kb[g * D_];
#pragma unroll 8
    for (int d = 0; d < D_; d++) a += kk[d] * vr[d * RK_];
    pk[(((size_t)b * S_ + s) * NH_ + h) * RK_ + r] = a;
  }
  if (tid < 128) {
    const int g = tid >> 4, r = tid & 15;
    float a = 0.f;
    const float* zv = &Zv[(size_t)g * D_ * RK_ + r];
    const float* vv = &vb[g * D_];
#pragma unroll 8
    for (int d = 0; d < D_; d++) a += vv[d] * zv[d * RK_];
    pv[(((size_t)b * S_ + s) * NKV_ + g) * RK_ + r] = a;
  }
}

// ---------------------------------------------------------------------------
// Expand pk -> k_rot bf16 (B,NH,S,D) with RoPE.
// ---------------------------------------------------------------------------
__global__ __launch_bounds__(256) void expand_k(const float* __restrict__ pk,
                                                const float* __restrict__ Vr,
                                                const float* __restrict__ cosT,
                                                const float* __restrict__ sinT,
                                                unsigned short* __restrict__ kr) {
  const int s0 = blockIdx.x * 32, h = blockIdx.y, b = blockIdx.z;
  const int tid = threadIdx.x;
  __shared__ float pkS[32][17];
  if (tid < 128) {
    const int r_ = tid >> 2, c4 = (tid & 3) * 4;
    float4 v = *(const float4*)&pk[(((size_t)b * S_ + s0 + r_) * NH_ + h) * RK_ + c4];
    pkS[r_][c4 + 0] = v.x; pkS[r_][c4 + 1] = v.y;
    pkS[r_][c4 + 2] = v.z; pkS[r_][c4 + 3] = v.w;
  }
  __syncthreads();
  const int row = tid >> 3, dl = tid & 7;
  float kh[16];
#pragma unroll
  for (int j = 0; j < 16; j++) {
    const int d = dl + 8 * j;
    const float4* w = (const float4*)&Vr[((size_t)h * D_ + d) * RK_];
    float a = 0.f;
#pragma unroll
    for (int q4 = 0; q4 < 4; q4++) {
      float4 wv = w[q4];
      a += pkS[row][q4 * 4 + 0] * wv.x + pkS[row][q4 * 4 + 1] * wv.y
         + pkS[row][q4 * 4 + 2] * wv.z + pkS[row][q4 * 4 + 3] * wv.w;
    }
    kh[j] = a;
  }
  const int pos = s0 + row;
  const size_t o = (((size_t)b * NH_ + h) * S_ + pos) * D_;
#pragma unroll
  for (int j = 0; j < 8; j++) {
    const int d = dl + 8 * j;
    const float c = cosT[pos * 64 + d], sn = sinT[pos * 64 + d];
    kr[o + d]      = f2bf(kh[j] * c - kh[j + 8] * sn);
    kr[o + d + 64] = f2bf(kh[j] * sn + kh[j + 8] * c);
  }
}

// ---------------------------------------------------------------------------
// Expand pv -> v_hat bf16 (B,NKV,S,D).
// ---------------------------------------------------------------------------
__global__ __launch_bounds__(256) void expand_v(const float* __restrict__ pv,
                                                const float* __restrict__ Zv,
                                                unsigned short* __restrict__ vh) {
  const int s0 = blockIdx.x * 32, g = blockIdx.y, b = blockIdx.z;
  const int tid = threadIdx.x;
  __shared__ float pvS[32][17];
  if (tid < 128) {
    const int r_ = tid >> 2, c4 = (tid & 3) * 4;
    float4 v = *(const float4*)&pv[(((size_t)b * S_ + s0 + r_) * NKV_ + g) * RK_ + c4];
    pvS[r_][c4 + 0] = v.x; pvS[r_][c4 + 1] = v.y;
    pvS[r_][c4 + 2] = v.z; pvS[r_][c4 + 3] = v.w;
  }
  __syncthreads();
  const int row = tid >> 3, dl = tid & 7;
  const size_t o = (((size_t)b * NKV_ + g) * S_ + s0 + row) * D_;
#pragma unroll
  for (int j = 0; j < 16; j++) {
    const int d = dl + 8 * j;
    const float4* w = (const float4*)&Zv[((size_t)g * D_ + d) * RK_];
    float a = 0.f;
#pragma unroll
    for (int q4 = 0; q4 < 4; q4++) {
      float4 wv = w[q4];
      a += pvS[row][q4 * 4 + 0] * wv.x + pvS[row][q4 * 4 + 1] * wv.y
         + pvS[row][q4 * 4 + 2] * wv.z + pvS[row][q4 * 4 + 3] * wv.w;
    }
    vh[o + d] = f2bf(a);
  }
}

// ---------------------------------------------------------------------------
// MFMA flash attention. Block = (qt, h, b), 256 thr = 4 waves.
// Wave w owns q rows qt*128 + w*32 .. +31. KV tile = 32 keys.
// K staged swizzled via global_load_lds; V transposed in LDS (Vt[128][40]);
// P via per-wave LDS buffer (Ps[w][32][40]).
// ---------------------------------------------------------------------------
__global__ __launch_bounds__(256) void attn_mfma(const unsigned short* __restrict__ q,
                                                 const unsigned short* __restrict__ kr,
                                                 const unsigned short* __restrict__ vh,
                                                 unsigned short* __restrict__ out) {
  const int qt = (int)(gridDim.x - 1) - (int)blockIdx.x;  // big blocks first
  const int h = blockIdx.y, b = blockIdx.z;
  const int g = h >> 1;
  const int tid = threadIdx.x;
  const int w = tid >> 6, l = tid & 63, lg = l >> 4, ll = l & 15;

  __shared__ unsigned short Klds[32 * 128];   // swizzled rows of 256B (16 slots)
  __shared__ unsigned short Vt[128 * 40];     // transposed V, padded rows (80B)
  __shared__ unsigned short Ps[4][32 * 40];   // per-wave P, padded rows

  const int qr0 = qt * 128 + w * 32;

  // Q fragments (held in registers for the whole kernel)
  s16x8 qf[2][4];
#pragma unroll
  for (int mi = 0; mi < 2; ++mi)
#pragma unroll
    for (int ks = 0; ks < 4; ++ks)
      qf[mi][ks] = *(const s16x8*)&q[(((size_t)b * S_ + qr0 + mi * 16 + ll) * NH_ + h) * D_ + ks * 32 + lg * 8];

  f32x4 o[2][8];
#pragma unroll
  for (int mi = 0; mi < 2; ++mi)
#pragma unroll
    for (int nd = 0; nd < 8; ++nd) o[mi][nd] = (f32x4){0.f, 0.f, 0.f, 0.f};
  float m_[2][4], l_[2][4];
#pragma unroll
  for (int mi = 0; mi < 2; ++mi)
#pragma unroll
    for (int j = 0; j < 4; ++j) { m_[mi][j] = NEGBIG; l_[mi][j] = 0.f; }

  const int ktmax = qt * 4 + 3;   // block loop bound
  const int kmy   = qt * 4 + w;   // wave causal bound (diagonal tile index)

  for (int kt = 0; kt <= ktmax; ++kt) {
    __syncthreads();   // previous tile's consumers done
    // ---- stage K (swizzled source -> linear LDS dest)
    {
      const unsigned short* kbase = &kr[(((size_t)b * NH_ + h) * S_ + kt * 32) * D_];
#pragma unroll
      for (int c = 0; c < 2; ++c) {
        const int row = c * 16 + (tid >> 4);
        const int slot = tid & 15;
        const int ss = slot ^ (row & 7);
        const unsigned short* src = kbase + row * D_ + ss * 8;
        char* dst = ((char*)Klds) + c * 4096 + w * 1024;
        __builtin_amdgcn_global_load_lds((const AS1 void*)src, (AS3 void*)dst, 16, 0, 0);
      }
      // ---- stage V transposed: thread owns key-pair kp, d-block dblk
      const int kp = tid & 15, dblk = tid >> 4;
      const unsigned short* v0 = &vh[(((size_t)b * NKV_ + g) * S_ + kt * 32 + 2 * kp) * D_ + dblk * 8];
      ushort8 va = *(const ushort8*)v0;
      ushort8 vb = *(const ushort8*)(v0 + D_);
#pragma unroll
      for (int j = 0; j < 8; ++j) {
        const unsigned int pk2 = (unsigned int)va[j] | ((unsigned int)vb[j] << 16);
        *(unsigned int*)&Vt[(dblk * 8 + j) * 40 + 2 * kp] = pk2;
      }
    }
    __syncthreads();

    if (kt <= kmy) {
      // ---- QK^T: S[32 q][32 k]
      f32x4 s[2][2];
#pragma unroll
      for (int mi = 0; mi < 2; ++mi)
#pragma unroll
        for (int ni = 0; ni < 2; ++ni) s[mi][ni] = (f32x4){0.f, 0.f, 0.f, 0.f};
#pragma unroll
      for (int ni = 0; ni < 2; ++ni) {
#pragma unroll
        for (int ks = 0; ks < 4; ++ks) {
          const int row = ni * 16 + ll;
          const int ps = (ks * 4 + lg) ^ (row & 7);
          const s16x8 kf = *(const s16x8*)&Klds[row * 128 + ps * 8];
          s[0][ni] = __builtin_amdgcn_mfma_f32_16x16x32_bf16(qf[0][ks], kf, s[0][ni], 0, 0, 0);
          s[1][ni] = __builtin_amdgcn_mfma_f32_16x16x32_bf16(qf[1][ks], kf, s[1][ni], 0, 0, 0);
        }
      }

      // ---- mask + online softmax (rows owned per (mi,j), spread over 16-lane group)
      const bool diag = (kt == kmy);
#pragma unroll
      for (int mi = 0; mi < 2; ++mi) {
#pragma unroll
        for (int j = 0; j < 4; ++j) {
          float v0 = s[mi][0][j] * SCALING_;
          float v1 = s[mi][1][j] * SCALING_;
          if (diag) {
            const int qrel = mi * 16 + lg * 4 + j;
            if (ll > qrel)      v0 = NEGBIG;
            if (16 + ll > qrel) v1 = NEGBIG;
          }
          float mt = fmaxf(v0, v1);
          mt = fmaxf(mt, __shfl_xor(mt, 1));
          mt = fmaxf(mt, __shfl_xor(mt, 2));
          mt = fmaxf(mt, __shfl_xor(mt, 4));
          mt = fmaxf(mt, __shfl_xor(mt, 8));
          const float mnew = fmaxf(m_[mi][j], mt);
          const float al = __expf(m_[mi][j] - mnew);
          m_[mi][j] = mnew;
          const float p0 = __expf(v0 - mnew);
          const float p1 = __expf(v1 - mnew);
          float rs = p0 + p1;
          rs += __shfl_xor(rs, 1);
          rs += __shfl_xor(rs, 2);
          rs += __shfl_xor(rs, 4);
          rs += __shfl_xor(rs, 8);
          l_[mi][j] = l_[mi][j] * al + rs;
#pragma unroll
          for (int nd = 0; nd < 8; ++nd) o[mi][nd][j] *= al;
          const int prow = mi * 16 + lg * 4 + j;
          Ps[w][prow * 40 + ll]      = f2bf(p0);
          Ps[w][prow * 40 + 16 + ll] = f2bf(p1);
        }
      }

      // ---- PV: O += P[32x32] @ V[32x128]   (DS same-wave ordering covers P)
      s16x8 pa[2];
      pa[0] = *(const s16x8*)&Ps[w][(ll) * 40 + lg * 8];
      pa[1] = *(const s16x8*)&Ps[w][(16 + ll) * 40 + lg * 8];
#pragma unroll
      for (int nd = 0; nd < 8; ++nd) {
        const s16x8 vb2 = *(const s16x8*)&Vt[(nd * 16 + ll) * 40 + lg * 8];
        o[0][nd] = __builtin_amdgcn_mfma_f32_16x16x32_bf16(pa[0], vb2, o[0][nd], 0, 0, 0);
        o[1][nd] = __builtin_amdgcn_mfma_f32_16x16x32_bf16(pa[1], vb2, o[1][nd], 0, 0, 0);
      }
    }
  }

  // ---- epilogue: normalize and store (B,S,NH*D)
#pragma unroll
  for (int mi = 0; mi < 2; ++mi)
#pragma unroll
    for (int j = 0; j < 4; ++j) {
      const float inv = 1.f / l_[mi][j];
      const size_t rowg = (size_t)b * S_ + qr0 + mi * 16 + lg * 4 + j;
      unsigned short* op = &out[rowg * (NH_ * D_) + h * D_ + ll];
#pragma unroll
      for (int nd = 0; nd < 8; ++nd) op[nd * 16] = f2bf(o[mi][nd][j] * inv);
    }
}

// ---------------------------------------------------------------------------
// Host launch
// ---------------------------------------------------------------------------
extern "C" void kernel_launch(void* const* d_in, const int* in_sizes, int n_in,
                              void* d_out, int out_size, void* d_ws, size_t ws_size,
                              hipStream_t stream) {
  const float* hidden = (const float*)d_in[0];
  const float* cosT   = (const float*)d_in[1];
  const float* sinT   = (const float*)d_in[2];
  const float* W_q    = (const float*)d_in[5];
  const float* W_k    = (const float*)d_in[6];
  const float* W_v    = (const float*)d_in[7];
  const float* W_o    = (const float*)d_in[8];
  const float* Vr     = (const float*)d_in[9];
  const float* Zv     = (const float*)d_in[10];
  float* out = (float*)d_out;

  // workspace map (bytes), peak 130,023,424 (verified available in round 2)
  char* ws = (char*)d_ws;
  unsigned short* hb     = (unsigned short*)(ws + 0);           // 33,554,432 hidden bf16 -> later attn_b
  unsigned short* attn_b = (unsigned short*)(ws + 0);           // alias (hb dead after v-gemm)
  unsigned short* q_b    = (unsigned short*)(ws + 33554432);    // 33,554,432 (B,S,NH,D)
  unsigned short* kraw_b = (unsigned short*)(ws + 67108864);    // 16,777,216 -> later k_rot[0:..]
  unsigned short* vraw_b = (unsigned short*)(ws + 83886080);    // 16,777,216 -> later k_rot[..:]
  unsigned short* kr_b   = (unsigned short*)(ws + 67108864);    // 33,554,432 (B,NH,S,D)
  unsigned short* vh_b   = (unsigned short*)(ws + 100663296);   // 16,777,216 (B,NKV,S,D)
  unsigned short* WR1    = (unsigned short*)(ws + 117440512);   //  8,388,608 Wq / later Wo bf16, pk_f
  unsigned short* WR2    = (unsigned short*)(ws + 125829120);   //  4,194,304 Wk then Wv bf16, pv_f
  float*          pk_f   = (float*)(ws + 117440512);            //  8,388,608 (B,S,NH,RK)
  float*          pv_f   = (float*)(ws + 125829120);            //  4,194,304 (B,S,NKV,RV)

  const int M = B_ * S_;  // 8192

  // 1) dtype conversions
  cvt_bf16<<<2048, 256, 0, stream>>>(hidden, hb, (B_ * S_ * HID_) / 8);
  cvt_bf16<<<2048, 256, 0, stream>>>(W_q, WR1, (HID_ * HID_) / 8);
  cvt_bf16<<<2048, 256, 0, stream>>>(W_k, WR2, (NKV_ * D_ * HID_) / 8);

  // 2) projections (MFMA)
  gemm_mfma<true><<<dim3(16, 64), 256, 0, stream>>>(hb, WR1, q_b,    M, NH_ * D_,  HID_);
  gemm_mfma<true><<<dim3( 8, 64), 256, 0, stream>>>(hb, WR2, kraw_b, M, NKV_ * D_, HID_);
  cvt_bf16<<<2048, 256, 0, stream>>>(W_v, WR2, (NKV_ * D_ * HID_) / 8);   // Wk done
  gemm_mfma<true><<<dim3( 8, 64), 256, 0, stream>>>(hb, WR2, vraw_b, M, NKV_ * D_, HID_);

  // 3) rope(q) in place
  rope_q<<<(B_ * S_ * NH_ * 64) / 256, 256, 0, stream>>>(q_b, cosT, sinT);

  // 4) low-rank coefficients (into WR1/WR2 regions, weights dead)
  pkpv_make<<<dim3(S_, B_), 256, 0, stream>>>(kraw_b, vraw_b, Vr, Zv, pk_f, pv_f);

  // 5) expand K (+rope) and V  (k_rot overwrites dead kraw/vraw region)
  expand_k<<<dim3(S_ / 32, NH_, B_), 256, 0, stream>>>(pk_f, Vr, cosT, sinT, kr_b);
  expand_v<<<dim3(S_ / 32, NKV_, B_), 256, 0, stream>>>(pv_f, Zv, vh_b);

  // 6) convert Wo (pk dead after expand_k)
  cvt_bf16<<<2048, 256, 0, stream>>>(W_o, WR1, (HID_ * HID_) / 8);

  // 7) MFMA flash attention (attn_b overwrites dead hb)
  attn_mfma<<<dim3(S_ / 128, NH_, B_), 256, 0, stream>>>(q_b, kr_b, vh_b, attn_b);

  // 8) output projection (f32 out)
  gemm_mfma<false><<<dim3(16, 64), 256, 0, stream>>>(attn_b, WR1, out, M, HID_, HID_);
}

// Round 4
// 832.787 us; speedup vs baseline: 7.3610x; 1.1427x over previous
//
#include <hip/hip_runtime.h>

typedef unsigned short ushort8 __attribute__((ext_vector_type(8)));
typedef short s16x8 __attribute__((ext_vector_type(8)));
typedef float f32x4 __attribute__((ext_vector_type(4)));

#define AS1 __attribute__((address_space(1)))
#define AS3 __attribute__((address_space(3)))

#define B_    4
#define S_    2048
#define HID_  2048
#define NH_   16
#define NKV_  8
#define D_    128
#define RK_   16
#define SCALING_ 0.08838834764831845f   // 128^-0.5
#define NEGBIG   -1.0e30f

__device__ __forceinline__ float bf2f(unsigned short u) {
  union { unsigned int i; float f; } x; x.i = ((unsigned int)u) << 16; return x.f;
}
__device__ __forceinline__ unsigned short f2bf(float f) {
  union { float f; unsigned int i; } x; x.f = f;
  unsigned int r = x.i + 0x7fffu + ((x.i >> 16) & 1u);
  return (unsigned short)(r >> 16);
}

// ---------------------------------------------------------------------------
// f32 -> bf16 conversion, 8 elems/thread, grid-stride.
// ---------------------------------------------------------------------------
__global__ __launch_bounds__(256) void cvt_bf16(const float* __restrict__ in,
                                                unsigned short* __restrict__ out,
                                                int n8) {
  int i = blockIdx.x * 256 + threadIdx.x;
  const int stride = gridDim.x * 256;
  for (; i < n8; i += stride) {
    const float4 a = ((const float4*)in)[i * 2];
    const float4 b = ((const float4*)in)[i * 2 + 1];
    ushort8 u;
    u[0] = f2bf(a.x); u[1] = f2bf(a.y); u[2] = f2bf(a.z); u[3] = f2bf(a.w);
    u[4] = f2bf(b.x); u[5] = f2bf(b.y); u[6] = f2bf(b.z); u[7] = f2bf(b.w);
    *(ushort8*)&out[i * 8] = u;
  }
}

// ---------------------------------------------------------------------------
// MFMA GEMM: C[M,N] = A[M,K] @ B[N,K]^T, A,B bf16, C f32 or bf16.
// 128x128 tile, BK=64, 4 waves, XCD chunk swizzle on flattened grid.
// ---------------------------------------------------------------------------
template<bool CBF>
__global__ __launch_bounds__(256) void gemm_mfma(const unsigned short* __restrict__ A,
                                                 const unsigned short* __restrict__ Bb,
                                                 void* __restrict__ C_,
                                                 int M, int N, int K) {
  __shared__ unsigned short Ash[128 * 64];
  __shared__ unsigned short Bsh[128 * 64];
  const int tid = threadIdx.x;
  const int w = tid >> 6, l = tid & 63, lg = l >> 4, ll = l & 15;
  const int wr = w >> 1, wc = w & 1;
  // XCD chunk swizzle (grid size divisible by 8)
  const int flat = blockIdx.y * gridDim.x + blockIdx.x;
  const int cpx = (gridDim.x * gridDim.y) >> 3;
  const int swz = (flat & 7) * cpx + (flat >> 3);
  const int bm = (swz / gridDim.x) * 128, bn = (swz % gridDim.x) * 128;

  f32x4 acc[4][4];
#pragma unroll
  for (int i = 0; i < 4; i++)
#pragma unroll
    for (int j = 0; j < 4; j++) acc[i][j] = (f32x4){0.f, 0.f, 0.f, 0.f};

  const int srow = tid >> 3;
  const int sslot = tid & 7;

  for (int k0 = 0; k0 < K; k0 += 64) {
    __syncthreads();
#pragma unroll
    for (int c = 0; c < 4; ++c) {
      const int row = c * 32 + srow;
      const int ss = sslot ^ (row & 7);
      const unsigned short* srcA = &A[(size_t)(bm + row) * K + k0 + ss * 8];
      const unsigned short* srcB = &Bb[(size_t)(bn + row) * K + k0 + ss * 8];
      char* dstA = ((char*)Ash) + c * 4096 + w * 1024;
      char* dstB = ((char*)Bsh) + c * 4096 + w * 1024;
      __builtin_amdgcn_global_load_lds((const AS1 void*)srcA, (AS3 void*)dstA, 16, 0, 0);
      __builtin_amdgcn_global_load_lds((const AS1 void*)srcB, (AS3 void*)dstB, 16, 0, 0);
    }
    __syncthreads();

#pragma unroll
    for (int ks = 0; ks < 2; ++ks) {
      s16x8 af[4], bf_[4];
#pragma unroll
      for (int mi = 0; mi < 4; ++mi) {
        const int row = wr * 64 + mi * 16 + ll;
        af[mi] = *(const s16x8*)&Ash[row * 64 + (((ks * 4 + lg) ^ (row & 7)) * 8)];
      }
#pragma unroll
      for (int ni = 0; ni < 4; ++ni) {
        const int row = wc * 64 + ni * 16 + ll;
        bf_[ni] = *(const s16x8*)&Bsh[row * 64 + (((ks * 4 + lg) ^ (row & 7)) * 8)];
      }
#pragma unroll
      for (int mi = 0; mi < 4; ++mi)
#pragma unroll
        for (int ni = 0; ni < 4; ++ni)
          acc[mi][ni] = __builtin_amdgcn_mfma_f32_16x16x32_bf16(af[mi], bf_[ni], acc[mi][ni], 0, 0, 0);
    }
  }

#pragma unroll
  for (int mi = 0; mi < 4; ++mi)
#pragma unroll
    for (int ni = 0; ni < 4; ++ni)
#pragma unroll
      for (int j = 0; j < 4; ++j) {
        const int row = bm + wr * 64 + mi * 16 + lg * 4 + j;
        const int col = bn + wc * 64 + ni * 16 + ll;
        if (CBF) ((unsigned short*)C_)[(size_t)row * N + col] = f2bf(acc[mi][ni][j]);
        else     ((float*)C_)[(size_t)row * N + col] = acc[mi][ni][j];
      }
}

// ---------------------------------------------------------------------------
// In-place RoPE on bf16 q, folding in SCALING (q only feeds attention).
// ---------------------------------------------------------------------------
__global__ __launch_bounds__(256) void rope_q(unsigned short* __restrict__ q,
                                              const float* __restrict__ cosT,
                                              const float* __restrict__ sinT) {
  const int p = blockIdx.x * 256 + threadIdx.x;
  const int d = p & 63;
  const int h = (p >> 6) & 15;
  const int s = (p >> 10) & 2047;
  const int b = p >> 21;
  const size_t base = (((size_t)b * S_ + s) * NH_ + h) * D_ + d;
  const float x1 = bf2f(q[base]), x2 = bf2f(q[base + 64]);
  const float c = cosT[s * 64 + d], sn = sinT[s * 64 + d];
  q[base]      = f2bf((x1 * c - x2 * sn) * SCALING_);
  q[base + 64] = f2bf((x1 * sn + x2 * c) * SCALING_);
}

// ---------------------------------------------------------------------------
// pk / pv low-rank coefficients. Block per (s,b), 256 threads.
// ---------------------------------------------------------------------------
__global__ __launch_bounds__(256) void pkpv_make(const unsigned short* __restrict__ k_raw,
                                                 const unsigned short* __restrict__ v_raw,
                                                 const float* __restrict__ Vr,
                                                 const float* __restrict__ Zv,
                                                 float* __restrict__ pk,
                                                 float* __restrict__ pv) {
  const int s = blockIdx.x, b = blockIdx.y;
  const int tid = threadIdx.x;
  __shared__ float kb[NKV_ * D_];
  __shared__ float vb[NKV_ * D_];
  {
    const size_t o = ((size_t)b * S_ + s) * (NKV_ * D_) + tid * 4;
    ushort4 ku = *(const ushort4*)&k_raw[o];
    kb[tid * 4 + 0] = bf2f(ku.x); kb[tid * 4 + 1] = bf2f(ku.y);
    kb[tid * 4 + 2] = bf2f(ku.z); kb[tid * 4 + 3] = bf2f(ku.w);
    ushort4 vu = *(const ushort4*)&v_raw[o];
    vb[tid * 4 + 0] = bf2f(vu.x); vb[tid * 4 + 1] = bf2f(vu.y);
    vb[tid * 4 + 2] = bf2f(vu.z); vb[tid * 4 + 3] = bf2f(vu.w);
  }
  __syncthreads();
  {
    const int h = tid >> 4, r = tid & 15, g = h >> 1;
    float a = 0.f;
    const float* vr = &Vr[(size_t)h * D_ * RK_ + r];
    const float* kk = &kb[g * D_];
#pragma unroll 8
    for (int d = 0; d < D_; d++) a += kk[d] * vr[d * RK_];
    pk[(((size_t)b * S_ + s) * NH_ + h) * RK_ + r] = a;
  }
  if (tid < 128) {
    const int g = tid >> 4, r = tid & 15;
    float a = 0.f;
    const float* zv = &Zv[(size_t)g * D_ * RK_ + r];
    const float* vv = &vb[g * D_];
#pragma unroll 8
    for (int d = 0; d < D_; d++) a += vv[d] * zv[d * RK_];
    pv[(((size_t)b * S_ + s) * NKV_ + g) * RK_ + r] = a;
  }
}

// ---------------------------------------------------------------------------
// Expand pk -> k_rot bf16 (B,NH,S,D) with RoPE.
// ---------------------------------------------------------------------------
__global__ __launch_bounds__(256) void expand_k(const float* __restrict__ pk,
                                                const float* __restrict__ Vr,
                                                const float* __restrict__ cosT,
                                                const float* __restrict__ sinT,
                                                unsigned short* __restrict__ kr) {
  const int s0 = blockIdx.x * 32, h = blockIdx.y, b = blockIdx.z;
  const int tid = threadIdx.x;
  __shared__ float pkS[32][17];
  if (tid < 128) {
    const int r_ = tid >> 2, c4 = (tid & 3) * 4;
    float4 v = *(const float4*)&pk[(((size_t)b * S_ + s0 + r_) * NH_ + h) * RK_ + c4];
    pkS[r_][c4 + 0] = v.x; pkS[r_][c4 + 1] = v.y;
    pkS[r_][c4 + 2] = v.z; pkS[r_][c4 + 3] = v.w;
  }
  __syncthreads();
  const int row = tid >> 3, dl = tid & 7;
  float kh[16];
#pragma unroll
  for (int j = 0; j < 16; j++) {
    const int d = dl + 8 * j;
    const float4* w = (const float4*)&Vr[((size_t)h * D_ + d) * RK_];
    float a = 0.f;
#pragma unroll
    for (int q4 = 0; q4 < 4; q4++) {
      float4 wv = w[q4];
      a += pkS[row][q4 * 4 + 0] * wv.x + pkS[row][q4 * 4 + 1] * wv.y
         + pkS[row][q4 * 4 + 2] * wv.z + pkS[row][q4 * 4 + 3] * wv.w;
    }
    kh[j] = a;
  }
  const int pos = s0 + row;
  const size_t o = (((size_t)b * NH_ + h) * S_ + pos) * D_;
#pragma unroll
  for (int j = 0; j < 8; j++) {
    const int d = dl + 8 * j;
    const float c = cosT[pos * 64 + d], sn = sinT[pos * 64 + d];
    kr[o + d]      = f2bf(kh[j] * c - kh[j + 8] * sn);
    kr[o + d + 64] = f2bf(kh[j] * sn + kh[j + 8] * c);
  }
}

// ---------------------------------------------------------------------------
// Expand pv -> v_hat bf16 (B,NKV,S,D).
// ---------------------------------------------------------------------------
__global__ __launch_bounds__(256) void expand_v(const float* __restrict__ pv,
                                                const float* __restrict__ Zv,
                                                unsigned short* __restrict__ vh) {
  const int s0 = blockIdx.x * 32, g = blockIdx.y, b = blockIdx.z;
  const int tid = threadIdx.x;
  __shared__ float pvS[32][17];
  if (tid < 128) {
    const int r_ = tid >> 2, c4 = (tid & 3) * 4;
    float4 v = *(const float4*)&pv[(((size_t)b * S_ + s0 + r_) * NKV_ + g) * RK_ + c4];
    pvS[r_][c4 + 0] = v.x; pvS[r_][c4 + 1] = v.y;
    pvS[r_][c4 + 2] = v.z; pvS[r_][c4 + 3] = v.w;
  }
  __syncthreads();
  const int row = tid >> 3, dl = tid & 7;
  const size_t o = (((size_t)b * NKV_ + g) * S_ + s0 + row) * D_;
#pragma unroll
  for (int j = 0; j < 16; j++) {
    const int d = dl + 8 * j;
    const float4* w = (const float4*)&Zv[((size_t)g * D_ + d) * RK_];
    float a = 0.f;
#pragma unroll
    for (int q4 = 0; q4 < 4; q4++) {
      float4 wv = w[q4];
      a += pvS[row][q4 * 4 + 0] * wv.x + pvS[row][q4 * 4 + 1] * wv.y
         + pvS[row][q4 * 4 + 2] * wv.z + pvS[row][q4 * 4 + 3] * wv.w;
    }
    vh[o + d] = f2bf(a);
  }
}

// ---------------------------------------------------------------------------
// MFMA flash attention v2. Block = 256 thr = 4 waves, 128 q-rows (32/wave).
// KV tile = 64 keys, double-buffered K (global_load_lds, pre-swizzled src)
// + reg-staged V (issue-early/write-late), ONE barrier per tile.
// Defer-max online softmax (THR=8), per-lane partial l, cvt_pk P-pack.
// LDS: K 2x16KB + Vt 2x16KB + Ps 16KB = 80KB -> 2 blocks/CU.
// ---------------------------------------------------------------------------
__global__ __launch_bounds__(256) void attn_mfma(const unsigned short* __restrict__ q,
                                                 const unsigned short* __restrict__ kr,
                                                 const unsigned short* __restrict__ vh,
                                                 unsigned short* __restrict__ out) {
  // XCD chunk swizzle over flattened (qt,h,b) grid of 1024
  const int flat = ((int)blockIdx.z * 16 + (int)blockIdx.y) * 16 + (int)blockIdx.x;
  const int swz = (flat & 7) * 128 + (flat >> 3);
  const int qt = 15 - (swz & 15);        // big blocks first within chunk
  const int h = (swz >> 4) & 15;
  const int b = swz >> 8;
  const int g = h >> 1;
  const int tid = threadIdx.x;
  const int w = tid >> 6, l = tid & 63, lg = l >> 4, ll = l & 15;

  __shared__ unsigned short Klds[2][64 * 128];  // swizzled (slot^row&7 of 16 slots)
  __shared__ unsigned short Vt[2][128 * 64];    // transposed V, swizzled (8 slots)
  __shared__ unsigned short Ps[4][32 * 64];     // per-wave P, swizzled (8 slots)

  const int qr0 = qt * 128 + w * 32;
  const int ktmax = 2 * qt + 1;
  const int kmy = 2 * qt + (w >> 1);

  // Q fragments (pre-scaled by rope_q)
  s16x8 qf[2][4];
#pragma unroll
  for (int mi = 0; mi < 2; ++mi)
#pragma unroll
    for (int ks = 0; ks < 4; ++ks)
      qf[mi][ks] = *(const s16x8*)&q[(((size_t)b * S_ + qr0 + mi * 16 + ll) * NH_ + h) * D_ + ks * 32 + lg * 8];

  f32x4 o[2][8];
#pragma unroll
  for (int mi = 0; mi < 2; ++mi)
#pragma unroll
    for (int nd = 0; nd < 8; ++nd) o[mi][nd] = (f32x4){0.f, 0.f, 0.f, 0.f};
  float m_[2][4], l_[2][4];
#pragma unroll
  for (int mi = 0; mi < 2; ++mi)
#pragma unroll
    for (int j = 0; j < 4; ++j) { m_[mi][j] = NEGBIG; l_[mi][j] = 0.f; }

  const unsigned short* kbase = &kr[(((size_t)b * NH_ + h) * S_) * D_];
  const unsigned short* vbase = &vh[(((size_t)b * NKV_ + g) * S_) * D_];
  const int vk = (tid & 31) * 2, d0v = (tid >> 5) * 16;

  // ---- prologue: stage tile 0
  ushort8 va0, va1, vb0, vb1;
  {
#pragma unroll
    for (int c = 0; c < 4; ++c) {
      const int ro = c * 16 + w * 4 + lg;
      const int ss = ll ^ (ro & 7);
      const unsigned short* src = kbase + ro * D_ + ss * 8;
      char* dst = ((char*)&Klds[0][0]) + c * 4096 + w * 1024;
      __builtin_amdgcn_global_load_lds((const AS1 void*)src, (AS3 void*)dst, 16, 0, 0);
    }
    const unsigned short* v0 = vbase + (size_t)vk * D_ + d0v;
    va0 = *(const ushort8*)v0; va1 = *(const ushort8*)(v0 + 8);
    vb0 = *(const ushort8*)(v0 + D_); vb1 = *(const ushort8*)(v0 + D_ + 8);
#pragma unroll
    for (int j = 0; j < 8; ++j) {
      const int d1 = d0v + j, d2 = d0v + 8 + j;
      *(unsigned int*)&Vt[0][d1 * 64 + (((vk >> 3) ^ (d1 & 7)) * 8) + (vk & 7)] =
          (unsigned int)va0[j] | ((unsigned int)vb0[j] << 16);
      *(unsigned int*)&Vt[0][d2 * 64 + (((vk >> 3) ^ (d2 & 7)) * 8) + (vk & 7)] =
          (unsigned int)va1[j] | ((unsigned int)vb1[j] << 16);
    }
  }
  __syncthreads();

  for (int kt = 0; kt <= ktmax; ++kt) {
    const int p = kt & 1;
    // ---- issue next-tile staging (K direct to LDS, V to regs)
    if (kt < ktmax) {
      const unsigned short* kb2 = kbase + (size_t)(kt + 1) * 64 * D_;
#pragma unroll
      for (int c = 0; c < 4; ++c) {
        const int ro = c * 16 + w * 4 + lg;
        const int ss = ll ^ (ro & 7);
        const unsigned short* src = kb2 + ro * D_ + ss * 8;
        char* dst = ((char*)&Klds[p ^ 1][0]) + c * 4096 + w * 1024;
        __builtin_amdgcn_global_load_lds((const AS1 void*)src, (AS3 void*)dst, 16, 0, 0);
      }
      const unsigned short* v0 = vbase + (size_t)((kt + 1) * 64 + vk) * D_ + d0v;
      va0 = *(const ushort8*)v0; va1 = *(const ushort8*)(v0 + 8);
      vb0 = *(const ushort8*)(v0 + D_); vb1 = *(const ushort8*)(v0 + D_ + 8);
    }

    if (kt <= kmy) {
      // ---- QK^T: S[32 q][64 k]
      f32x4 s[2][4];
#pragma unroll
      for (int mi = 0; mi < 2; ++mi)
#pragma unroll
        for (int ni = 0; ni < 4; ++ni) s[mi][ni] = (f32x4){0.f, 0.f, 0.f, 0.f};
#pragma unroll
      for (int ks = 0; ks < 4; ++ks) {
#pragma unroll
        for (int ni = 0; ni < 4; ++ni) {
          const int row = ni * 16 + ll;
          const s16x8 kf = *(const s16x8*)&Klds[p][row * 128 + (((ks * 4 + lg) ^ (row & 7)) * 8)];
          s[0][ni] = __builtin_amdgcn_mfma_f32_16x16x32_bf16(qf[0][ks], kf, s[0][ni], 0, 0, 0);
          s[1][ni] = __builtin_amdgcn_mfma_f32_16x16x32_bf16(qf[1][ks], kf, s[1][ni], 0, 0, 0);
        }
      }

      // ---- mask + local max
      const bool diag = (kt == kmy);
      float lm[2][4];
#pragma unroll
      for (int mi = 0; mi < 2; ++mi)
#pragma unroll
        for (int j = 0; j < 4; ++j) {
          if (diag) {
            const int qg = qr0 + mi * 16 + lg * 4 + j;
#pragma unroll
            for (int ni = 0; ni < 4; ++ni)
              if (kt * 64 + ni * 16 + ll > qg) s[mi][ni][j] = NEGBIG;
          }
          lm[mi][j] = fmaxf(fmaxf(s[mi][0][j], s[mi][1][j]),
                            fmaxf(s[mi][2][j], s[mi][3][j]));
        }
      float excess = lm[0][0] - m_[0][0];
#pragma unroll
      for (int mi = 0; mi < 2; ++mi)
#pragma unroll
        for (int j = 0; j < 4; ++j) excess = fmaxf(excess, lm[mi][j] - m_[mi][j]);
      const bool slow = __any(excess > 8.0f);

#pragma unroll
      for (int mi = 0; mi < 2; ++mi)
#pragma unroll
        for (int j = 0; j < 4; ++j) {
          float ps_[4];
          if (slow) {
            float mt = lm[mi][j];
            mt = fmaxf(mt, __shfl_xor(mt, 1));
            mt = fmaxf(mt, __shfl_xor(mt, 2));
            mt = fmaxf(mt, __shfl_xor(mt, 4));
            mt = fmaxf(mt, __shfl_xor(mt, 8));
            const float mnew = fmaxf(m_[mi][j], mt);
            const float al = __expf(m_[mi][j] - mnew);
            m_[mi][j] = mnew;
            float sum = 0.f;
#pragma unroll
            for (int ni = 0; ni < 4; ++ni) { ps_[ni] = __expf(s[mi][ni][j] - mnew); sum += ps_[ni]; }
            l_[mi][j] = l_[mi][j] * al + sum;
#pragma unroll
            for (int nd = 0; nd < 8; ++nd) o[mi][nd][j] *= al;
          } else {
            float sum = 0.f;
#pragma unroll
            for (int ni = 0; ni < 4; ++ni) { ps_[ni] = __expf(s[mi][ni][j] - m_[mi][j]); sum += ps_[ni]; }
            l_[mi][j] += sum;
          }
          const int prow = mi * 16 + lg * 4 + j;
#pragma unroll
          for (int nq = 0; nq < 2; ++nq) {
            unsigned int u;
            asm("v_cvt_pk_bf16_f32 %0, %1, %2" : "=v"(u) : "v"(ps_[nq * 2]), "v"(ps_[nq * 2 + 1]));
            const int c0 = nq * 32 + ll, c1 = nq * 32 + 16 + ll;
            Ps[w][prow * 64 + (((c0 >> 3) ^ (prow & 7)) * 8) + (ll & 7)] = (unsigned short)u;
            Ps[w][prow * 64 + (((c1 >> 3) ^ (prow & 7)) * 8) + (ll & 7)] = (unsigned short)(u >> 16);
          }
        }

      // ---- PV: O += P[32x64] @ V[64x128]
      s16x8 pa[2][2];
#pragma unroll
      for (int mi = 0; mi < 2; ++mi)
#pragma unroll
        for (int ks2 = 0; ks2 < 2; ++ks2) {
          const int prow = mi * 16 + ll;
          pa[mi][ks2] = *(const s16x8*)&Ps[w][prow * 64 + (((ks2 * 4 + lg) ^ (prow & 7)) * 8)];
        }
#pragma unroll
      for (int nd = 0; nd < 8; ++nd) {
#pragma unroll
        for (int ks2 = 0; ks2 < 2; ++ks2) {
          const int vr = nd * 16 + ll;
          const s16x8 vbf = *(const s16x8*)&Vt[p][vr * 64 + (((ks2 * 4 + lg) ^ (vr & 7)) * 8)];
          o[0][nd] = __builtin_amdgcn_mfma_f32_16x16x32_bf16(pa[0][ks2], vbf, o[0][nd], 0, 0, 0);
          o[1][nd] = __builtin_amdgcn_mfma_f32_16x16x32_bf16(pa[1][ks2], vbf, o[1][nd], 0, 0, 0);
        }
      }
    }

    // ---- write next tile's V (regs -> LDS), then single barrier
    if (kt < ktmax) {
#pragma unroll
      for (int j = 0; j < 8; ++j) {
        const int d1 = d0v + j, d2 = d0v + 8 + j;
        *(unsigned int*)&Vt[p ^ 1][d1 * 64 + (((vk >> 3) ^ (d1 & 7)) * 8) + (vk & 7)] =
            (unsigned int)va0[j] | ((unsigned int)vb0[j] << 16);
        *(unsigned int*)&Vt[p ^ 1][d2 * 64 + (((vk >> 3) ^ (d2 & 7)) * 8) + (vk & 7)] =
            (unsigned int)va1[j] | ((unsigned int)vb1[j] << 16);
      }
    }
    __syncthreads();
  }

  // ---- epilogue: reduce partial l, normalize, store (B,S,NH*D)
#pragma unroll
  for (int mi = 0; mi < 2; ++mi)
#pragma unroll
    for (int j = 0; j < 4; ++j) {
      float ls = l_[mi][j];
      ls += __shfl_xor(ls, 1);
      ls += __shfl_xor(ls, 2);
      ls += __shfl_xor(ls, 4);
      ls += __shfl_xor(ls, 8);
      const float inv = 1.f / ls;
      const size_t rowg = (size_t)b * S_ + qr0 + mi * 16 + lg * 4 + j;
      unsigned short* op = &out[rowg * (NH_ * D_) + h * D_ + ll];
#pragma unroll
      for (int nd = 0; nd < 8; ++nd) op[nd * 16] = f2bf(o[mi][nd][j] * inv);
    }
}

// ---------------------------------------------------------------------------
// Host launch
// ---------------------------------------------------------------------------
extern "C" void kernel_launch(void* const* d_in, const int* in_sizes, int n_in,
                              void* d_out, int out_size, void* d_ws, size_t ws_size,
                              hipStream_t stream) {
  const float* hidden = (const float*)d_in[0];
  const float* cosT   = (const float*)d_in[1];
  const float* sinT   = (const float*)d_in[2];
  const float* W_q    = (const float*)d_in[5];
  const float* W_k    = (const float*)d_in[6];
  const float* W_v    = (const float*)d_in[7];
  const float* W_o    = (const float*)d_in[8];
  const float* Vr     = (const float*)d_in[9];
  const float* Zv     = (const float*)d_in[10];
  float* out = (float*)d_out;

  char* ws = (char*)d_ws;
  unsigned short* hb     = (unsigned short*)(ws + 0);
  unsigned short* attn_b = (unsigned short*)(ws + 0);
  unsigned short* q_b    = (unsigned short*)(ws + 33554432);
  unsigned short* kraw_b = (unsigned short*)(ws + 67108864);
  unsigned short* vraw_b = (unsigned short*)(ws + 83886080);
  unsigned short* kr_b   = (unsigned short*)(ws + 67108864);
  unsigned short* vh_b   = (unsigned short*)(ws + 100663296);
  unsigned short* WR1    = (unsigned short*)(ws + 117440512);
  unsigned short* WR2    = (unsigned short*)(ws + 125829120);
  float*          pk_f   = (float*)(ws + 117440512);
  float*          pv_f   = (float*)(ws + 125829120);

  const int M = B_ * S_;

  cvt_bf16<<<2048, 256, 0, stream>>>(hidden, hb, (B_ * S_ * HID_) / 8);
  cvt_bf16<<<2048, 256, 0, stream>>>(W_q, WR1, (HID_ * HID_) / 8);
  cvt_bf16<<<2048, 256, 0, stream>>>(W_k, WR2, (NKV_ * D_ * HID_) / 8);

  gemm_mfma<true><<<dim3(16, 64), 256, 0, stream>>>(hb, WR1, q_b,    M, NH_ * D_,  HID_);
  gemm_mfma<true><<<dim3( 8, 64), 256, 0, stream>>>(hb, WR2, kraw_b, M, NKV_ * D_, HID_);
  cvt_bf16<<<2048, 256, 0, stream>>>(W_v, WR2, (NKV_ * D_ * HID_) / 8);
  gemm_mfma<true><<<dim3( 8, 64), 256, 0, stream>>>(hb, WR2, vraw_b, M, NKV_ * D_, HID_);

  rope_q<<<(B_ * S_ * NH_ * 64) / 256, 256, 0, stream>>>(q_b, cosT, sinT);

  pkpv_make<<<dim3(S_, B_), 256, 0, stream>>>(kraw_b, vraw_b, Vr, Zv, pk_f, pv_f);

  expand_k<<<dim3(S_ / 32, NH_, B_), 256, 0, stream>>>(pk_f, Vr, cosT, sinT, kr_b);
  expand_v<<<dim3(S_ / 32, NKV_, B_), 256, 0, stream>>>(pv_f, Zv, vh_b);

  cvt_bf16<<<2048, 256, 0, stream>>>(W_o, WR1, (HID_ * HID_) / 8);

  attn_mfma<<<dim3(16, 16, 4), 256, 0, stream>>>(q_b, kr_b, vh_b, attn_b);

  gemm_mfma<false><<<dim3(16, 64), 256, 0, stream>>>(attn_b, WR1, out, M, HID_, HID_);
}